// Round 9
// baseline (503.850 us; speedup 1.0000x reference)
//
#include <hip/hip_runtime.h>
#include <hip/hip_fp16.h>

#define VOCAB 32000
#define D 256
#define NSTEPS 12
#define BATCH 8
#define SEQ 512

// Uniform scan chunking (validated R6/R7): 64 chunks/batch, OUTLEN 8, WARM 12.
#define OUTLEN 8
#define WARM 12
#define ITERS (OUTLEN + WARM)    // 20
#define NCHUNK 64                // 64 chunks x 4 batch-pairs = 256 blocks

typedef _Float16 f16x8 __attribute__((ext_vector_type(8)));
typedef float f32x4 __attribute__((ext_vector_type(4)));

// ---- ws layout: A_pre (2 MB) | BpreH (16.384 MB) | BpreL (16.384 MB) ----
#define A_TILES 32               // 4096/128
#define BN_TILES 250             // 32000/128
#define TILE_IMG 16384           // 128 rows x 64 k x 2B, swizzled image
#define A_BYTES ((size_t)A_TILES * 4 * TILE_IMG)
#define B_BYTES ((size_t)BN_TILES * 4 * TILE_IMG)

// gelu(x) = 0.5 x (1 + erf(x/sqrt(2))); erf via A&S 7.1.26 (|err|<=1.5e-7).
__device__ __forceinline__ float gelu_fast(float x) {
    float y = x * 0.70710678118654752440f;
    float a = fabsf(y);
    float t = __builtin_amdgcn_rcpf(fmaf(0.3275911f, a, 1.0f));
    float p = fmaf(t, 1.061405429f, -1.453152027f);
    p = fmaf(t, p, 1.421413741f);
    p = fmaf(t, p, -0.284496736f);
    p = fmaf(t, p, 0.254829592f);
    p *= t;
    float e = __expf(-a * a);
    float erf_y = copysignf(fmaf(-p, e, 1.0f), y);
    return 0.5f * x * (1.0f + erf_y);
}

// cross-lane helpers (all VALU): xor1/xor2 quad_perm, row rotate by 4/8.
__device__ __forceinline__ float dpp_xor1(float v) {
    int r = __builtin_amdgcn_update_dpp(0, __float_as_int(v), 0xB1, 0xf, 0xf, true);
    return __int_as_float(r);
}
__device__ __forceinline__ float dpp_xor2(float v) {
    int r = __builtin_amdgcn_update_dpp(0, __float_as_int(v), 0x4E, 0xf, 0xf, true);
    return __int_as_float(r);
}
__device__ __forceinline__ float dpp_ror4(float v) {
    int r = __builtin_amdgcn_update_dpp(0, __float_as_int(v), 0x124, 0xf, 0xf, true);
    return __int_as_float(r);
}
__device__ __forceinline__ float dpp_ror8(float v) {
    int r = __builtin_amdgcn_update_dpp(0, __float_as_int(v), 0x128, 0xf, 0xf, true);
    return __int_as_float(r);
}

__device__ __forceinline__ float quadreduce(float a0, float a1, float a2, float a3, int jc) {
    float k01 = (jc & 1) ? a1 : a0, s01 = (jc & 1) ? a0 : a1;
    float r01 = k01 + dpp_xor1(s01);
    float k23 = (jc & 1) ? a3 : a2, s23 = (jc & 1) ? a2 : a3;
    float r23 = k23 + dpp_xor1(s23);
    float k = (jc & 2) ? r23 : r01, sx = (jc & 2) ? r01 : r23;
    float v = k + dpp_xor2(sx);
    v += dpp_ror4(v);
    v += dpp_ror8(v);
    return v;
}

// store one scan output element into the pre-swizzled f16 A image.
// image: tile (nrow>>7, i>>6); byte a = row*128 + ((col16 ^ (row&7))<<4) + (i&7)*2
__device__ __forceinline__ void storeA(char* Apre, int nrow, int i, float v) {
    const int bm = nrow >> 7, row = nrow & 127;
    const int kt = i >> 6;
    const int c16 = ((i & 63) >> 3) ^ (row & 7);
    const int a = row * 128 + (c16 << 4) + (i & 7) * 2;
    *(_Float16*)(Apre + ((size_t)(bm * 4 + kt)) * TILE_IMG + a) = (_Float16)v;
}

__device__ __forceinline__ void split8(float4 a, float4 b, f16x8& hi, f16x8& lo) {
    float v[8] = {a.x, a.y, a.z, a.w, b.x, b.y, b.z, b.w};
    #pragma unroll
    for (int j = 0; j < 8; ++j) {
        _Float16 h = (_Float16)v[j];
        hi[j] = h;
        lo[j] = (_Float16)(v[j] - (float)h);
    }
}

// async global->LDS, 16 B per lane. LDS dest = wave-uniform base + lane*16.
__device__ __forceinline__ void gload16(const void* g, void* l) {
    __builtin_amdgcn_global_load_lds(
        (const __attribute__((address_space(1))) void*)g,
        (__attribute__((address_space(3))) void*)l, 16, 0, 0);
}

// ---------------------------------------------------------------------------
// Phase A scan, DUAL-STREAM (R6 structure); outputs stored as f16 into the
// pre-swizzled A image (A needs hi only — validated since R4).
// ---------------------------------------------------------------------------
__global__ __launch_bounds__(1024) void scan_kernel(
    const int* __restrict__ ids, const float* __restrict__ emb,
    const float* __restrict__ W, const float* __restrict__ ps,
    char* __restrict__ Apre)
{
    const int bid = (int)blockIdx.x;          // 0..255
    const int c  = bid & 63;
    const int b0 = bid >> 6;                  // streams b0, b0+4
    const int b1 = b0 + 4;
    const int t = (int)threadIdx.x;
    const int og = t >> 4;
    const int jc = t & 15;
    const int i_mine = og * 4 + (jc & 3);
    const bool writer = (jc < 4);

    float4 wreg[4][4];
    #pragma unroll
    for (int m = 0; m < 4; ++m) {
        const float4* wrow = (const float4*)(W + (og * 4 + m) * D + jc * 16);
        #pragma unroll
        for (int q = 0; q < 4; ++q) wreg[m][q] = wrow[q];
    }

    __shared__ __align__(16) float sbuf0[2][16 * 20];
    __shared__ __align__(16) float sbuf1[2][16 * 20];

    const int first_out = c * OUTLEN;
    const int pstart = first_out - WARM;      // may be negative

    float psr[NSTEPS];
    #pragma unroll
    for (int s = 0; s < NSTEPS; ++s) psr[s] = ps[s];

    const int raddr = jc * 20;
    const int waddr = (i_mine >> 4) * 20 + (i_mine & 15);

    float prev0 = 0.0f, prev1 = 0.0f;
    const int p0 = (pstart > 0) ? pstart : 0;
    float cur0 = emb[(size_t)ids[b0 * SEQ + p0] * D + i_mine];
    float cur1 = emb[(size_t)ids[b1 * SEQ + p0] * D + i_mine];
    if (writer) { sbuf0[0][waddr] = cur0; sbuf1[0][waddr] = cur1; }
    __syncthreads();

    for (int it = 0; it < ITERS; ++it) {
        const int pos = pstart + it;
        int pn = pos + 1;
        if (pn < 0) pn = 0;
        if (pn > SEQ - 1) pn = SEQ - 1;       // clamp (R5 OOB fix)
        float nxt0 = emb[(size_t)ids[b0 * SEQ + pn] * D + i_mine];
        float nxt1 = emb[(size_t)ids[b1 * SEQ + pn] * D + i_mine];
        const float ctx = (pos > 0) ? (1.0f / (float)(pos + 1)) : 0.0f;
        #pragma unroll
        for (int s = 0; s < NSTEPS; ++s) {
            const int rb = s & 1;
            const float4* sp0 = (const float4*)&sbuf0[rb][raddr];
            const float4* sp1 = (const float4*)&sbuf1[rb][raddr];
            float a0 = 0.f, a1 = 0.f, a2 = 0.f, a3 = 0.f;
            float c0 = 0.f, c1 = 0.f, c2 = 0.f, c3 = 0.f;
            #pragma unroll
            for (int q = 0; q < 4; ++q) {
                float4 sv = sp0[q];
                float4 tv = sp1[q];
                a0 = fmaf(sv.x, wreg[0][q].x, a0); a0 = fmaf(sv.y, wreg[0][q].y, a0);
                a0 = fmaf(sv.z, wreg[0][q].z, a0); a0 = fmaf(sv.w, wreg[0][q].w, a0);
                a1 = fmaf(sv.x, wreg[1][q].x, a1); a1 = fmaf(sv.y, wreg[1][q].y, a1);
                a1 = fmaf(sv.z, wreg[1][q].z, a1); a1 = fmaf(sv.w, wreg[1][q].w, a1);
                a2 = fmaf(sv.x, wreg[2][q].x, a2); a2 = fmaf(sv.y, wreg[2][q].y, a2);
                a2 = fmaf(sv.z, wreg[2][q].z, a2); a2 = fmaf(sv.w, wreg[2][q].w, a2);
                a3 = fmaf(sv.x, wreg[3][q].x, a3); a3 = fmaf(sv.y, wreg[3][q].y, a3);
                a3 = fmaf(sv.z, wreg[3][q].z, a3); a3 = fmaf(sv.w, wreg[3][q].w, a3);
                c0 = fmaf(tv.x, wreg[0][q].x, c0); c0 = fmaf(tv.y, wreg[0][q].y, c0);
                c0 = fmaf(tv.z, wreg[0][q].z, c0); c0 = fmaf(tv.w, wreg[0][q].w, c0);
                c1 = fmaf(tv.x, wreg[1][q].x, c1); c1 = fmaf(tv.y, wreg[1][q].y, c1);
                c1 = fmaf(tv.z, wreg[1][q].z, c1); c1 = fmaf(tv.w, wreg[1][q].w, c1);
                c2 = fmaf(tv.x, wreg[2][q].x, c2); c2 = fmaf(tv.y, wreg[2][q].y, c2);
                c2 = fmaf(tv.z, wreg[2][q].z, c2); c2 = fmaf(tv.w, wreg[2][q].w, c2);
                c3 = fmaf(tv.x, wreg[3][q].x, c3); c3 = fmaf(tv.y, wreg[3][q].y, c3);
                c3 = fmaf(tv.z, wreg[3][q].z, c3); c3 = fmaf(tv.w, wreg[3][q].w, c3);
            }
            float v0 = quadreduce(a0, a1, a2, a3, jc);
            float v1 = quadreduce(c0, c1, c2, c3, jc);
            float x0 = fmaf(psr[s], cur0, v0);
            float x1 = fmaf(psr[s], cur1, v1);
            cur0 = gelu_fast(x0) + ctx * prev0;
            cur1 = gelu_fast(x1) + ctx * prev1;
            if (writer) {
                sbuf0[rb ^ 1][waddr] = (s == NSTEPS - 1) ? nxt0 : cur0;
                sbuf1[rb ^ 1][waddr] = (s == NSTEPS - 1) ? nxt1 : cur1;
            }
            __syncthreads();
        }
        prev0 = cur0; prev1 = cur1;
        if (pos >= first_out && writer) {
            storeA(Apre, b0 * SEQ + pos, i_mine, cur0);
            storeA(Apre, b1 * SEQ + pos, i_mine, cur1);
        }
        cur0 = nxt0; cur1 = nxt1;
    }
}

// ---------------------------------------------------------------------------
// One-time B pre-split: out_W f32 -> f16 hi/lo, stored in the per-tile
// swizzled LDS-image layout so the GEMM can global_load_lds it linearly.
// chunk g -> (bn = g>>12, kt = (g>>10)&3, image byte a = (g&1023)*16);
// source cols = kt*64 + (((a>>4)&7) ^ ((a>>7)&7))*8.
// ---------------------------------------------------------------------------
__global__ __launch_bounds__(256) void bsplit_kernel(
    const float* __restrict__ Bw, char* __restrict__ BpreH, char* __restrict__ BpreL)
{
    const int g = (int)blockIdx.x * 256 + (int)threadIdx.x;   // 0..1,023,999
    const int a = (g & 1023) << 4;
    const int kt = (g >> 10) & 3;
    const int bn = g >> 12;
    const int row = a >> 7;
    const int c16 = ((a >> 4) & 7) ^ (row & 7);
    const float* src = Bw + ((size_t)(bn * 128 + row)) * D + kt * 64 + c16 * 8;
    float4 v0 = ((const float4*)src)[0];
    float4 v1 = ((const float4*)src)[1];
    f16x8 hi, lo;
    split8(v0, v1, hi, lo);
    *(f16x8*)(BpreH + (size_t)g * 16) = hi;
    *(f16x8*)(BpreL + (size_t)g * 16) = lo;
}

// ---------------------------------------------------------------------------
// Phase B: C[4096][32000] = A @ B^T + bias.  2-term f16 split (Ahi*Bhi +
// Ahi*Blo), 128x128x64 tiles, 8 waves, wave tile 64x32.  PRE: all three LDS
// tiles staged via global_load_lds (16B) from pre-swizzled images — no
// staging VALU at all.  Fallback (!PRE): A async, B reg-staged + split.
// ---------------------------------------------------------------------------
#define BM 128
#define BN 128
#define BK 64
#define GT 512

template <bool PRE>
__global__ __launch_bounds__(GT) void gemm_kernel(
    const char* __restrict__ Apre, const float* __restrict__ Bw,
    const char* __restrict__ BpreH, const char* __restrict__ BpreL,
    const float* __restrict__ bias, float* __restrict__ C)
{
    __shared__ __align__(16) _Float16 Ahi[BM * BK];
    __shared__ __align__(16) _Float16 Bhi[BN * BK], Blo[BN * BK];

    const int tid = (int)threadIdx.x;
    const int bn = blockIdx.x, bm = blockIdx.y;
    const int lane = tid & 63, wave = tid >> 6;
    const int wm = wave >> 2, wn = wave & 3;
    const int l15 = lane & 15, lh = lane >> 4;

    // async staging: wave w covers image bytes [w*2048, w*2048+2048)
    const int so = wave * 2048 + lane * 16;
    const char* aS  = Apre  + ((size_t)bm * 4) * TILE_IMG + so;
    const char* bhS = BpreH + ((size_t)bn * 4) * TILE_IMG + so;
    const char* blS = BpreL + ((size_t)bn * 4) * TILE_IMG + so;

    // fallback B staging coords
    const int sr = tid >> 2, sg = tid & 3;
    const float* bsrc = Bw + (size_t)(bn * BN + sr) * D + sg * 16;

    f32x4 acc[4][2] = {};

    for (int kt = 0; kt < 4; ++kt) {
        gload16(aS + kt * TILE_IMG,        (char*)Ahi + wave * 2048);
        gload16(aS + kt * TILE_IMG + 1024, (char*)Ahi + wave * 2048 + 1024);
        if (PRE) {
            gload16(bhS + kt * TILE_IMG,        (char*)Bhi + wave * 2048);
            gload16(bhS + kt * TILE_IMG + 1024, (char*)Bhi + wave * 2048 + 1024);
            gload16(blS + kt * TILE_IMG,        (char*)Blo + wave * 2048);
            gload16(blS + kt * TILE_IMG + 1024, (char*)Blo + wave * 2048 + 1024);
        } else {
            const float* bp = bsrc + kt * BK;
            float4 bv[4];
            #pragma unroll
            for (int q = 0; q < 4; ++q) bv[q] = ((const float4*)bp)[q];
            const int swz = (sr & 7) << 4;
            #pragma unroll
            for (int h = 0; h < 2; ++h) {
                const int off = (sr * 128 + sg * 32 + h * 16) ^ swz;
                f16x8 hi, lo;
                split8(bv[h * 2], bv[h * 2 + 1], hi, lo);
                *(f16x8*)((char*)Bhi + off) = hi;
                *(f16x8*)((char*)Blo + off) = lo;
            }
        }
        __syncthreads();

        #pragma unroll
        for (int ks = 0; ks < 2; ++ks) {
            f16x8 ah[4], bh[2], bl[2];
            #pragma unroll
            for (int mt = 0; mt < 4; ++mt) {
                const int row = wm * 64 + mt * 16 + l15;
                const int off = (row * 128 + ks * 64 + lh * 16) ^ ((row & 7) << 4);
                ah[mt] = *(const f16x8*)((const char*)Ahi + off);
            }
            #pragma unroll
            for (int nt = 0; nt < 2; ++nt) {
                const int row = wn * 32 + nt * 16 + l15;
                const int off = (row * 128 + ks * 64 + lh * 16) ^ ((row & 7) << 4);
                bh[nt] = *(const f16x8*)((const char*)Bhi + off);
                bl[nt] = *(const f16x8*)((const char*)Blo + off);
            }
            #pragma unroll
            for (int mt = 0; mt < 4; ++mt)
                #pragma unroll
                for (int nt = 0; nt < 2; ++nt) {
                    acc[mt][nt] = __builtin_amdgcn_mfma_f32_16x16x32_f16(ah[mt], bh[nt], acc[mt][nt], 0, 0, 0);
                    acc[mt][nt] = __builtin_amdgcn_mfma_f32_16x16x32_f16(ah[mt], bl[nt], acc[mt][nt], 0, 0, 0);
                }
        }
        __syncthreads();
    }

    #pragma unroll
    for (int nt = 0; nt < 2; ++nt) {
        const int col = bn * BN + wn * 32 + nt * 16 + l15;
        const float bv2 = bias[col];
        #pragma unroll
        for (int mt = 0; mt < 4; ++mt) {
            const int row0 = bm * BM + wm * 64 + mt * 16 + lh * 4;
            #pragma unroll
            for (int r2 = 0; r2 < 4; ++r2)
                C[(size_t)(row0 + r2) * VOCAB + col] = acc[mt][nt][r2] + bv2;
        }
    }
}

extern "C" void kernel_launch(void* const* d_in, const int* in_sizes, int n_in,
                              void* d_out, int out_size, void* d_ws, size_t ws_size,
                              hipStream_t stream)
{
    const int*   ids  = (const int*)d_in[0];
    const float* emb  = (const float*)d_in[1];
    const float* W    = (const float*)d_in[2];
    const float* ps   = (const float*)d_in[3];
    const float* outW = (const float*)d_in[4];
    const float* outb = (const float*)d_in[5];
    float* out = (float*)d_out;

    char* Apre  = (char*)d_ws;
    char* BpreH = Apre + A_BYTES;
    char* BpreL = BpreH + B_BYTES;
    const bool pre = ws_size >= A_BYTES + 2 * B_BYTES;

    if (pre)
        bsplit_kernel<<<dim3((BN_TILES * 4 * 1024) / 256), 256, 0, stream>>>(outW, BpreH, BpreL);
    scan_kernel<<<dim3(NCHUNK * (BATCH / 2)), 1024, 0, stream>>>(ids, emb, W, ps, Apre);
    if (pre)
        gemm_kernel<true><<<dim3(VOCAB / BN, (BATCH * SEQ) / BM), GT, 0, stream>>>(Apre, outW, BpreH, BpreL, outb, out);
    else
        gemm_kernel<false><<<dim3(VOCAB / BN, (BATCH * SEQ) / BM), GT, 0, stream>>>(Apre, outW, BpreH, BpreL, outb, out);
}